// Round 4
// baseline (284.230 us; speedup 1.0000x reference)
//
#include <hip/hip_runtime.h>
#include <hip/hip_cooperative_groups.h>
#include <math.h>

namespace cg = cooperative_groups;

// Problem constants (match reference)
#define T_LEN 4096
#define FIR_L 513
#define N_PHA 10
#define N_AMP 10
#define N_BANDS 20
#define N_BINS 18
#define BC 64            // B*C = 4*16

typedef __attribute__((ext_vector_type(8))) short short8;
typedef __attribute__((ext_vector_type(4))) float f32x4;

// Interleaved-complex skewed addresses for z (float index of re; im at +1).
// Even skew keeps 8-byte alignment for b64 LDS ops.
// Extent: ZA(4095)+2 = 8702 -> z region 8704 floats.
#define ZA(i) (((i) << 1) + ((((i) >> 4)) << 1))

// Global twiddle table (1024 complex). Written redundantly by phase-1 blocks
// (identical sincosf values -> benign race); visible to phase 2 via grid.sync.
__device__ float2 twg_dev[1024];

// float -> bf16 round-to-nearest-even
static __device__ __forceinline__ unsigned short f2bf(float x) {
    unsigned u = __float_as_uint(x);
    unsigned r = u + 0x7FFFu + ((u >> 16) & 1u);
    return (unsigned short)(r >> 16);
}

// storage index -> frequency after radix-4 DIF (base-4 digit reversal)
static __device__ __forceinline__ int digitrev12(int p) {
    unsigned rr = __brev((unsigned)p) >> 20;               // 12-bit bit reversal
    rr = ((rr & 0x555u) << 1) | ((rr & 0xAAAu) >> 1);      // swap bit pairs
    return (int)rr;
}

// twiddle fetch + double/sum-angle derivation
static __device__ __forceinline__ void tw_derive(const float2* tw, int m1,
        float& c1, float& s1, float& c2, float& s2, float& c3, float& s3) {
    const float2 w1 = tw[m1];
    c1 = w1.x; s1 = w1.y;
    s2 = 2.0f * s1 * c1;                 // double angle
    c2 = fmaf(-2.0f * s1, s1, 1.0f);
    c3 = c1 * c2 - s1 * s2;              // angle sum
    s3 = s1 * c2 + c1 * s2;
}

// u * e^{-i theta}, theta given as (c, s)
static __device__ __forceinline__ float2 cmul_em(float2 u, float c, float s) {
    return make_float2(u.x * c + u.y * s, u.y * c - u.x * s);
}

// forward radix-4 DIF butterfly (multiply by e^{-i theta})
static __device__ __forceinline__ void bf_fwd(float2& A, float2& B, float2& C, float2& D,
        float c1, float s1, float c2, float s2, float c3, float s3) {
    const float t0r = A.x + C.x, t0i = A.y + C.y;
    const float t1r = A.x - C.x, t1i = A.y - C.y;
    const float t2r = B.x + D.x, t2i = B.y + D.y;
    const float t3r = B.x - D.x, t3i = B.y - D.y;
    const float y0r = t0r + t2r,  y0i = t0i + t2i;
    const float u1r = t1r + t3i, u1i = t1i - t3r;   // t1 - i*t3
    const float u2r = t0r - t2r, u2i = t0i - t2i;
    const float u3r = t1r - t3i, u3i = t1i + t3r;   // t1 + i*t3
    A = make_float2(y0r, y0i);
    B = make_float2(u1r * c1 + u1i * s1, u1i * c1 - u1r * s1);
    C = make_float2(u2r * c2 + u2i * s2, u2i * c2 - u2r * s2);
    D = make_float2(u3r * c3 + u3i * s3, u3i * c3 - u3r * s3);
}

// inverse radix-4 DIT butterfly (multiply by e^{+i theta})
static __device__ __forceinline__ void bf_inv(float2& A, float2& B, float2& C, float2& D,
        float c1, float s1, float c2, float s2, float c3, float s3) {
    const float tbr = B.x * c1 - B.y * s1, tbi = B.y * c1 + B.x * s1;
    const float tcr = C.x * c2 - C.y * s2, tci = C.y * c2 + C.x * s2;
    const float tdr = D.x * c3 - D.y * s3, tdi = D.y * c3 + D.x * s3;
    const float ar = A.x, ai = A.y;
    A = make_float2(ar + tbr + tcr + tdr, ai + tbi + tci + tdi);
    B = make_float2(ar - tbi - tcr + tdi, ai + tbr - tci - tdr);   // a + i*tb - tc - i*td
    C = make_float2(ar - tbr + tcr - tdr, ai - tbi + tci - tdi);
    D = make_float2(ar + tbi - tcr - tdi, ai - tbr - tci + tdr);   // a - i*tb - tc + i*td
}

// ---------------------------------------------------------------------------
// Forward radix-4 DIF, natural -> base-4 digit-reversed, fused stage pairs
// (16 elements/thread in registers per pass). s0 = first stage (0 or 2).
// ---------------------------------------------------------------------------
static __device__ __forceinline__ void fft_fwd_passes(float* z, const float2* tw,
                                                      int tid, int s0) {
    for (int s = s0; s < 6; s += 2) {
        const int hl = 10 - 2 * s;
        const int h  = 1 << hl;
        const int h4 = h >> 2;
        const int kk = tid & (h4 - 1);
        const int g  = tid >> (hl - 2);
        const int i0 = (g << (hl + 2)) + kk;     // g*4h + kk
        float2 e[4][4];
#pragma unroll
        for (int j = 0; j < 4; ++j)
#pragma unroll
            for (int r = 0; r < 4; ++r)
                e[j][r] = *(const float2*)&z[ZA(i0 + j * h4 + r * h)];
        // stage s: butterfly over r for each j; twiddle m = (kk + j*h4) << 2s
#pragma unroll
        for (int j = 0; j < 4; ++j) {
            float c1, s1, c2, s2, c3, s3;
            tw_derive(tw, (kk + j * h4) << (2 * s), c1, s1, c2, s2, c3, s3);
            bf_fwd(e[j][0], e[j][1], e[j][2], e[j][3], c1, s1, c2, s2, c3, s3);
        }
        // stage s+1: butterfly over j for each r; single twiddle set kk << (2s+2)
        {
            float c1, s1, c2, s2, c3, s3;
            tw_derive(tw, kk << (2 * s + 2), c1, s1, c2, s2, c3, s3);
#pragma unroll
            for (int r = 0; r < 4; ++r)
                bf_fwd(e[0][r], e[1][r], e[2][r], e[3][r], c1, s1, c2, s2, c3, s3);
        }
#pragma unroll
        for (int j = 0; j < 4; ++j)
#pragma unroll
            for (int r = 0; r < 4; ++r)
                *(float2*)&z[ZA(i0 + j * h4 + r * h)] = e[j][r];
        __syncthreads();
    }
}

// ---------------------------------------------------------------------------
// Sparse fused pass 1 (stages 0+1) for the corr signal: the only nonzero
// inputs in this thread's 16-element set are F = corr[tid] (j=0,r=0) and
// Tl = corr[3840+tid] (j=3,r=3), both in registers. Value-identical to the
// dense path; skips z zero/stage, 16 LDS reads, and one barrier.
// ---------------------------------------------------------------------------
static __device__ __forceinline__ void fft_fwd_pass1_sparse(
        float* z, const float2* tw, int tid, float2 F, float2 Tl) {
    float c1, s1, c2, s2, c3, s3;
    // stage 0, j=0 (twiddle m = tid)
    tw_derive(tw, tid, c1, s1, c2, s2, c3, s3);
    float2 P[4];
    P[0] = F;
    P[1] = cmul_em(F, c1, s1);
    P[2] = cmul_em(F, c2, s2);
    P[3] = cmul_em(F, c3, s3);
    // stage 0, j=3 (twiddle m = tid+768): inputs (0,0,0,Tl) -> u=(Tl, i*Tl, -Tl, -i*Tl)
    tw_derive(tw, tid + 768, c1, s1, c2, s2, c3, s3);
    const float2 iT  = make_float2(-Tl.y,  Tl.x);
    const float2 nT  = make_float2(-Tl.x, -Tl.y);
    const float2 niT = make_float2( Tl.y, -Tl.x);
    float2 Q[4];
    Q[0] = Tl;
    Q[1] = cmul_em(iT,  c1, s1);
    Q[2] = cmul_em(nT,  c2, s2);
    Q[3] = cmul_em(niT, c3, s3);
    // stage 1 (twiddle m = 4*tid): butterfly (P,0,0,Q) over j, per r
    tw_derive(tw, tid << 2, c1, s1, c2, s2, c3, s3);
#pragma unroll
    for (int r = 0; r < 4; ++r) {
        const int ib = tid + (r << 10);
        const float2 A = make_float2(P[r].x + Q[r].x, P[r].y + Q[r].y);
        const float2 B = cmul_em(make_float2(P[r].x - Q[r].y, P[r].y + Q[r].x), c1, s1); // P + iQ
        const float2 C = cmul_em(make_float2(P[r].x - Q[r].x, P[r].y - Q[r].y), c2, s2); // P - Q
        const float2 D = cmul_em(make_float2(P[r].x + Q[r].y, P[r].y - Q[r].x), c3, s3); // P - iQ
        *(float2*)&z[ZA(ib)]        = A;
        *(float2*)&z[ZA(ib + 256)]  = B;
        *(float2*)&z[ZA(ib + 512)]  = C;
        *(float2*)&z[ZA(ib + 768)]  = D;
    }
}

// ---------------------------------------------------------------------------
// Inverse radix-4 DIT, base-4 digit-reversed -> natural (unscaled), fused
// stage pairs.
// ---------------------------------------------------------------------------
static __device__ __forceinline__ void fft_inv6(float* z, const float2* tw, int tid) {
#pragma unroll
    for (int s = 0; s < 6; s += 2) {
        const int L  = 1 << (2 * s);
        const int k  = tid & (L - 1);
        const int g  = tid >> (2 * s);
        const int i0 = (g << (2 * s + 4)) + k;   // g*16L + k
        float2 e[4][4];
#pragma unroll
        for (int j = 0; j < 4; ++j)
#pragma unroll
            for (int r = 0; r < 4; ++r)
                e[j][r] = *(const float2*)&z[ZA(i0 + j * L + (r << (2 * s + 2)))];
        // stage s: butterfly over j for each r; single twiddle set k << (10-2s)
        {
            float c1, s1, c2, s2, c3, s3;
            tw_derive(tw, k << (10 - 2 * s), c1, s1, c2, s2, c3, s3);
#pragma unroll
            for (int r = 0; r < 4; ++r)
                bf_inv(e[0][r], e[1][r], e[2][r], e[3][r], c1, s1, c2, s2, c3, s3);
        }
        // stage s+1: butterfly over r for each j; twiddle (k + j*L) << (8-2s)
#pragma unroll
        for (int j = 0; j < 4; ++j) {
            float c1, s1, c2, s2, c3, s3;
            tw_derive(tw, (k + j * L) << (8 - 2 * s), c1, s1, c2, s2, c3, s3);
            bf_inv(e[j][0], e[j][1], e[j][2], e[j][3], c1, s1, c2, s2, c3, s3);
        }
#pragma unroll
        for (int j = 0; j < 4; ++j)
#pragma unroll
            for (int r = 0; r < 4; ++r)
                *(float2*)&z[ZA(i0 + j * L + (r << (2 * s + 2)))] = e[j][r];
        __syncthreads();
    }
}

// ---------------------------------------------------------------------------
// Phase-1 unit: spectra. u < BC -> X[u] = FFT(x row); else Hf[u-BC] =
// FFT(circularly-placed correlation kernel h[n]=f[256-n]).
// ---------------------------------------------------------------------------
static __device__ void process_pre_unit(int u,
        const float* __restrict__ x, const float* __restrict__ filt,
        float2* __restrict__ Xs, float2* __restrict__ Hs,
        float* smem_f, int tid)
{
    float* z  = smem_f;
    float* fb = smem_f + 8704;

    __syncthreads();   // guard LDS reuse across grid-stride iterations

    if (u < BC) {
        const float* xrow = x + u * T_LEN;
        for (int i = tid; i < 4096; i += 256)
            *(float2*)&z[ZA(i)] = make_float2(xrow[i], 0.0f);
    } else {
        const int band = u - BC;
        for (int i = tid; i < FIR_L; i += 256) fb[i] = filt[band * FIR_L + i];
        __syncthreads();
        // h[n] = f[256-n] for n in [0,257); h[n] = f[4352-n] for n in [3840,4096)
        for (int i = tid; i < 4096; i += 256) {
            float hv = 0.0f;
            if (i < 257)        hv = fb[256 - i];
            else if (i >= 3840) hv = fb[4352 - i];
            *(float2*)&z[ZA(i)] = make_float2(hv, 0.0f);
        }
    }
    __syncthreads();

    fft_fwd_passes(z, twg_dev, tid, 0);

    float2* dst = (u < BC) ? (Xs + u * 4096) : (Hs + (u - BC) * 4096);
    for (int i = tid; i < 4096; i += 256)
        dst[i] = *(const float2*)&z[ZA(i)];
}

// ---------------------------------------------------------------------------
// Phase-2 unit: per (bc, band): analytic = IFFT( mask * (X*Hf + FFT(corr)) ).
// Verbatim round-2 spectral_main body. Safe across grid-stride iterations:
// first z write is behind the post-staging barrier.
// ---------------------------------------------------------------------------
static __device__ void process_main_unit(int u,
        const float* __restrict__ x, const float* __restrict__ filt,
        const float2* __restrict__ Xs, const float2* __restrict__ Hs,
        float* __restrict__ pha, unsigned short* __restrict__ amp_bf,
        float* smem_f, int tid)
{
    float* z  = smem_f;            // 8704 floats
    float* xe = smem_f + 8704;     // 512
    float* fb = smem_f + 9216;     // 513
    const int bc   = u / N_BANDS;
    const int band = u % N_BANDS;
    const float2* tw = twg_dev;

    const float* xrow = x + bc * T_LEN;
    for (int i = tid; i < 512; i += 256)
        xe[i] = (i < 256) ? xrow[i] : xrow[3584 + i];   // 3584+i = 3840+(i-256)
    for (int i = tid; i < FIR_L; i += 256) fb[i] = filt[band * FIR_L + i];
    __syncthreads();

    // ---- boundary correction (linear - circular), 257 balanced FMAs/thread
    float cf = 0.0f, ct = 0.0f;
    for (int l = 0; l <= 255 - tid; ++l)
        cf = fmaf(fb[l], xe[256 + tid + l], cf);
    for (int j = 0; j <= tid; ++j)
        ct = fmaf(fb[512 - tid + j], xe[j], ct);

    // ---- fwd FFT of corr: sparse pass 1 from registers, then dense passes
    fft_fwd_pass1_sparse(z, tw, tid, make_float2(-cf, 0.0f), make_float2(-ct, 0.0f));
    __syncthreads();
    fft_fwd_passes(z, tw, tid, 2);    // passes s=2,4

    // ---- pointwise: P = X*Hf + C, Hilbert mask, back into z
    const float2* Xrow = Xs + bc * 4096;
    const float2* Hrow = Hs + band * 4096;
    for (int i = tid; i < 4096; i += 256) {
        const float2 X = Xrow[i];
        const float2 H = Hrow[i];
        const float2 C = *(const float2*)&z[ZA(i)];
        float pr = X.x * H.x - X.y * H.y + C.x;
        float pi = X.x * H.y + X.y * H.x + C.y;
        const int f = digitrev12(i);
        const float mf = (f == 0 || f == 2048) ? 1.0f : (f < 2048 ? 2.0f : 0.0f);
        *(float2*)&z[ZA(i)] = make_float2(pr * mf, pi * mf);
    }
    __syncthreads();

    fft_inv6(z, tw, tid);    // analytic signal (unscaled by 1/N)

    // ---- emit phase (fp32) or amplitude (bf16)
    const float inv_n = 1.0f / 4096.0f;
    if (band < N_PHA) {
        float* dst = pha + (bc * N_PHA + band) * T_LEN;
        for (int i = tid; i < 4096; i += 256) {
            const float2 zz = *(const float2*)&z[ZA(i)];
            dst[i] = atan2f(zz.y, zz.x);         // scale cancels in atan2
        }
    } else {
        unsigned short* dst = amp_bf + (bc * N_AMP + (band - N_PHA)) * T_LEN;
        for (int i = tid; i < 4096; i += 256) {
            const float2 zz = *(const float2*)&z[ZA(i)];
            dst[i] = f2bf(sqrtf(zz.x * zz.x + zz.y * zz.y) * inv_n);
        }
    }
}

// ---------------------------------------------------------------------------
// Phase-3 unit: per (bc, pha-band): 3-hot soft phase binning + einsum via
// MFMA. Safe across grid-stride iterations (wbuf/psum writes are disjoint
// from the prior iteration's post-barrier asum reads).
// ---------------------------------------------------------------------------
static __device__ void process_bin_unit(int unit,
        const float* __restrict__ pha, const unsigned short* __restrict__ amp_bf,
        float* __restrict__ out, float* smem_f, int tid)
{
    unsigned int* wbuf = (unsigned int*)smem_f;   // [4][18*68] = 4896 words
    float* psum = smem_f + 4896;                  // [4][11][18] = 792
    float* asum = smem_f + 5688;                  // [11][18]    = 198

    const int lane = tid & 63;
    const int wv   = tid >> 6;        // 0..3
    const int bc   = unit / N_PHA;
    const int p    = unit % N_PHA;

    const float* phrow = pha + (bc * N_PHA + p) * T_LEN;
    const unsigned short* arow = amp_bf + bc * N_AMP * T_LEN;

    const float PI_F  = 3.14159274101257324f;
    const float INVD  = 2.8647889756541160f;   // 9/pi
    const float DELTA = 0.34906585039886590f;  // 2pi/18
    const float C1    = 12.184696791468343f;   // DELTA^2 / 0.01
    const float C2    = 69.813170079773180f;   // 2*DELTA / 0.01

    const int m_ = lane & 15;
    const int q_ = lane >> 4;
    const int n_ = lane & 15;

    short8 zero8;
#pragma unroll
    for (int j = 0; j < 8; ++j) zero8[j] = 0;
    short8 ones8;
#pragma unroll
    for (int j = 0; j < 8; ++j) ones8[j] = (short)0x3F80;   // bf16 1.0

    f32x4 acc0 = {0.f, 0.f, 0.f, 0.f};   // bins 0..15
    f32x4 acc1 = {0.f, 0.f, 0.f, 0.f};   // bins 16..17

    const int base_t = wv * 1024;
    unsigned int* wrow = wbuf + wv * 1224;
    unsigned short* wh = (unsigned short*)wrow;

    // hoist all phase loads (issue early, independent)
    float2 pp[8];
#pragma unroll
    for (int c = 0; c < 8; ++c)
        pp[c] = *(const float2*)&phrow[base_t + c * 128 + lane * 2];

    for (int chunk = 0; chunk < 8; ++chunk) {
        const int cb = base_t + chunk * 128;

        // prefetch this chunk's A fragments (latency overlaps softmax below)
        short8 af[4];
#pragma unroll
        for (int s = 0; s < 4; ++s) {
            const int tA = cb + s * 32 + q_ * 8;
            if (m_ < N_AMP)       af[s] = *(const short8*)(arow + m_ * T_LEN + tA);
            else if (m_ == N_AMP) af[s] = ones8;
            else                  af[s] = zero8;
        }

        // zero this lane's column in all 18 rows
#pragma unroll
        for (int k = 0; k < N_BINS; ++k)
            wrow[k * 68 + lane] = 0u;

        // 3-hot softmax, two samples
#pragma unroll
        for (int h = 0; h < 2; ++h) {
            const float ph = h ? pp[chunk].y : pp[chunk].x;
            float u  = (ph + PI_F) * INVD;       // in [0, 18]
            float jf = floorf(u);
            float d  = (u - jf - 0.5f) * DELTA;
            int j0 = (int)jf;
            if (j0 >= N_BINS) j0 -= N_BINS;      // ph == +pi wraps
            const int jm = (j0 == 0) ? N_BINS - 1 : j0 - 1;
            const int jp = (j0 == N_BINS - 1) ? 0 : j0 + 1;
            const float em = expf(-C1 - C2 * d);
            const float ep = expf(-C1 + C2 * d);
            const float inv = 1.0f / (1.0f + em + ep);
            wh[(j0 * 68 + lane) * 2 + h] = f2bf(inv);
            wh[(jm * 68 + lane) * 2 + h] = f2bf(em * inv);
            wh[(jp * 68 + lane) * 2 + h] = f2bf(ep * inv);
        }
        __builtin_amdgcn_wave_barrier();   // pin: w stores before frag reads

        // ---- 4 MFMA K-steps (K=32 each)
#pragma unroll
        for (int s = 0; s < 4; ++s) {
            const int woff = s * 16 + q_ * 4;
            short8 bfrag0 = *(const short8*)&wrow[n_ * 68 + woff];
            short8 bfrag1 = (n_ < 2)
                ? *(const short8*)&wrow[(16 + n_) * 68 + woff]
                : zero8;
            acc0 = __builtin_amdgcn_mfma_f32_16x16x32_bf16(af[s], bfrag0, acc0, 0, 0, 0);
            acc1 = __builtin_amdgcn_mfma_f32_16x16x32_bf16(af[s], bfrag1, acc1, 0, 0, 0);
        }
        __builtin_amdgcn_wave_barrier();   // pin: frag reads before next zeroing
    }

    // ---- per-wave C tiles (C/D: col=lane&15, row=(lane>>4)*4+reg)
#pragma unroll
    for (int r = 0; r < 4; ++r) {
        const int m = q_ * 4 + r;
        if (m < 11) {
            psum[(wv * 11 + m) * N_BINS + n_] = acc0[r];
            if (n_ < 2) psum[(wv * 11 + m) * N_BINS + 16 + n_] = acc1[r];
        }
    }
    __syncthreads();

    if (tid < 11 * N_BINS) {
        const int m = tid / N_BINS;
        const int k = tid % N_BINS;
        asum[tid] = psum[(0 * 11 + m) * N_BINS + k] + psum[(1 * 11 + m) * N_BINS + k]
                  + psum[(2 * 11 + m) * N_BINS + k] + psum[(3 * 11 + m) * N_BINS + k];
    }
    __syncthreads();

    if (tid < N_AMP) {
        float ma[N_BINS];
        float msum = 0.0f;
#pragma unroll
        for (int k = 0; k < N_BINS; ++k) {
            float m = asum[tid * N_BINS + k] / (asum[10 * N_BINS + k] + 1e-8f);
            ma[k] = m;
            msum += m;
        }
        const float inv = 1.0f / (msum + 1e-8f);
        float acc = 0.0f;
#pragma unroll
        for (int k = 0; k < N_BINS; ++k) {
            float pk = ma[k] * inv;
            acc = fmaf(pk, logf(pk + 1e-8f), acc);
        }
        const float logk = 2.89037175789124f;    // log(18)
        out[(bc * N_PHA + p) * N_AMP + tid] = (logk + acc) / logk;
    }
}

// ---------------------------------------------------------------------------
// Single cooperative kernel; ALL phases grid-stride so ANY grid size >= 1 is
// correct (R3 failure: phase-3 `if (b < 640)` silently dropped units when the
// grid came out < 640). LDS 38916 B -> 4 blocks/CU.
// ---------------------------------------------------------------------------
__global__ __launch_bounds__(256, 4) void pac_fused(
    const float* __restrict__ x,          // (BC, T)
    const float* __restrict__ filt,       // (20, 513)
    float2* __restrict__ Xs,              // (BC, 4096)
    float2* __restrict__ Hs,              // (20, 4096)
    float* __restrict__ pha,              // (BC, 10, T) fp32
    unsigned short* __restrict__ amp_bf,  // (BC, 10, T) bf16 bits
    float* __restrict__ out)              // (BC, 10, 10)
{
    __shared__ __align__(16) float smem_f[9729];   // 38916 B, overlaid per phase

    const int tid = threadIdx.x;
    const int b   = blockIdx.x;
    const int nb  = gridDim.x;
    cg::grid_group gridg = cg::this_grid();

    // ================= phase 1: spectra (84 units, grid-stride) ============
    if (b < BC + N_BANDS) {
        // redundant twiddle-table write (identical values across blocks);
        // own writes visible to this block after __syncthreads inside the
        // unit; cross-block visibility for phase 2 via grid.sync.
        for (int m = tid; m < 1024; m += 256) {
            float ang = (float)m * (6.283185307179586f / 4096.0f);
            float s, c;
            sincosf(ang, &s, &c);
            twg_dev[m] = make_float2(c, s);
        }
    }
    for (int u = b; u < BC + N_BANDS; u += nb)
        process_pre_unit(u, x, filt, Xs, Hs, smem_f, tid);
    gridg.sync();

    // ================= phase 2: main units (1280, grid-stride) =============
    for (int u = b; u < BC * N_BANDS; u += nb)
        process_main_unit(u, x, filt, Xs, Hs, pha, amp_bf, smem_f, tid);
    gridg.sync();

    // ================= phase 3: bin units (640, grid-stride) ===============
    for (int u = b; u < BC * N_PHA; u += nb)
        process_bin_unit(u, pha, amp_bf, out, smem_f, tid);
}

extern "C" void kernel_launch(void* const* d_in, const int* in_sizes, int n_in,
                              void* d_out, int out_size, void* d_ws, size_t ws_size,
                              hipStream_t stream) {
    const float* x    = (const float*)d_in[0];   // (4,16,4096) f32
    const float* filt = (const float*)d_in[1];   // (20,513) f32
    float* out = (float*)d_out;                  // (4,16,10,10) f32

    // ws layout: pha fp32 | amp bf16 | Xspec | Hspec  (~18.5 MB total)
    float* pha = (float*)d_ws;                               // BC*10*T fp32
    unsigned short* amp_bf = (unsigned short*)(pha + BC * N_PHA * T_LEN);
    float2* Xs = (float2*)(amp_bf + BC * N_AMP * T_LEN);     // BC*4096 cplx
    float2* Hs = Xs + BC * 4096;                             // 20*4096 cplx

    // cooperative grid: blocks/CU from the typed occupancy API, clamped to
    // [2,4] (LDS 38916 B allows 4 on the 160 KiB pool; 2 is always safely
    // co-resident). Grid-stride phases make ANY grid size correct.
    static int grid_blocks = 0;
    if (grid_blocks == 0) {
        int dev = 0;
        hipGetDevice(&dev);
        hipDeviceProp_t prop;
        int n_cu = 256;
        if (hipGetDeviceProperties(&prop, dev) == hipSuccess && prop.multiProcessorCount > 0)
            n_cu = prop.multiProcessorCount;
        int nb = 0;
        hipError_t e = hipOccupancyMaxActiveBlocksPerMultiprocessor(&nb, pac_fused, 256, 0);
        if (e != hipSuccess || nb < 1) nb = 2;   // conservative fallback
        if (nb > 4) nb = 4;
        long cap  = (long)nb * n_cu;
        long want = (long)(BC * N_BANDS);
        grid_blocks = (int)(cap < want ? cap : want);
        if (grid_blocks < 1) grid_blocks = 1;
    }

    void* args[] = {(void*)&x, (void*)&filt, (void*)&Xs, (void*)&Hs,
                    (void*)&pha, (void*)&amp_bf, (void*)&out};
    hipLaunchCooperativeKernel((const void*)pac_fused, dim3(grid_blocks), dim3(256),
                               args, 0, stream);
}

// Round 5
// 121.935 us; speedup vs baseline: 2.3310x; 2.3310x over previous
//
#include <hip/hip_runtime.h>
#include <math.h>

// Problem constants (match reference)
#define T_LEN 4096
#define FIR_L 513
#define N_PHA 10
#define N_AMP 10
#define N_BANDS 20
#define N_BINS 18
#define BC 64            // B*C = 4*16

typedef __attribute__((ext_vector_type(8))) short short8;
typedef __attribute__((ext_vector_type(4))) float f32x4;

// Interleaved-complex skewed addresses for z (float index of re; im at +1).
// Even skew keeps 8-byte alignment for b64 LDS ops.
// Extent: ZA(4095)+2 = 8702 -> z region 8704 floats.
#define ZA(i) (((i) << 1) + ((((i) >> 4)) << 1))

// Global twiddle table (1024 complex), written by spectral_pre's block 84
// with the same libm sincosf values as always -> bitwise-identical FFTs.
__device__ float2 twg_dev[1024];

// float -> bf16 round-to-nearest-even
static __device__ __forceinline__ unsigned short f2bf(float x) {
    unsigned u = __float_as_uint(x);
    unsigned r = u + 0x7FFFu + ((u >> 16) & 1u);
    return (unsigned short)(r >> 16);
}

// storage index -> frequency after radix-4 DIF (base-4 digit reversal)
static __device__ __forceinline__ int digitrev12(int p) {
    unsigned rr = __brev((unsigned)p) >> 20;               // 12-bit bit reversal
    rr = ((rr & 0x555u) << 1) | ((rr & 0xAAAu) >> 1);      // swap bit pairs
    return (int)rr;
}

// twiddle fetch + double/sum-angle derivation
static __device__ __forceinline__ void tw_derive(const float2* tw, int m1,
        float& c1, float& s1, float& c2, float& s2, float& c3, float& s3) {
    const float2 w1 = tw[m1];
    c1 = w1.x; s1 = w1.y;
    s2 = 2.0f * s1 * c1;                 // double angle
    c2 = fmaf(-2.0f * s1, s1, 1.0f);
    c3 = c1 * c2 - s1 * s2;              // angle sum
    s3 = s1 * c2 + c1 * s2;
}

// u * e^{-i theta}, theta given as (c, s)
static __device__ __forceinline__ float2 cmul_em(float2 u, float c, float s) {
    return make_float2(u.x * c + u.y * s, u.y * c - u.x * s);
}

// forward radix-4 DIF butterfly (multiply by e^{-i theta})
static __device__ __forceinline__ void bf_fwd(float2& A, float2& B, float2& C, float2& D,
        float c1, float s1, float c2, float s2, float c3, float s3) {
    const float t0r = A.x + C.x, t0i = A.y + C.y;
    const float t1r = A.x - C.x, t1i = A.y - C.y;
    const float t2r = B.x + D.x, t2i = B.y + D.y;
    const float t3r = B.x - D.x, t3i = B.y - D.y;
    const float y0r = t0r + t2r,  y0i = t0i + t2i;
    const float u1r = t1r + t3i, u1i = t1i - t3r;   // t1 - i*t3
    const float u2r = t0r - t2r, u2i = t0i - t2i;
    const float u3r = t1r - t3i, u3i = t1i + t3r;   // t1 + i*t3
    A = make_float2(y0r, y0i);
    B = make_float2(u1r * c1 + u1i * s1, u1i * c1 - u1r * s1);
    C = make_float2(u2r * c2 + u2i * s2, u2i * c2 - u2r * s2);
    D = make_float2(u3r * c3 + u3i * s3, u3i * c3 - u3r * s3);
}

// inverse radix-4 DIT butterfly (multiply by e^{+i theta})
static __device__ __forceinline__ void bf_inv(float2& A, float2& B, float2& C, float2& D,
        float c1, float s1, float c2, float s2, float c3, float s3) {
    const float tbr = B.x * c1 - B.y * s1, tbi = B.y * c1 + B.x * s1;
    const float tcr = C.x * c2 - C.y * s2, tci = C.y * c2 + C.x * s2;
    const float tdr = D.x * c3 - D.y * s3, tdi = D.y * c3 + D.x * s3;
    const float ar = A.x, ai = A.y;
    A = make_float2(ar + tbr + tcr + tdr, ai + tbi + tci + tdi);
    B = make_float2(ar - tbi - tcr + tdi, ai + tbr - tci - tdr);   // a + i*tb - tc - i*td
    C = make_float2(ar - tbr + tcr - tdr, ai - tbi + tci - tdi);
    D = make_float2(ar + tbi - tcr - tdi, ai - tbr - tci + tdr);   // a - i*tb - tc + i*td
}

// ---------------------------------------------------------------------------
// Forward radix-4 DIF, natural -> base-4 digit-reversed, fused stage pairs
// (16 elements/thread in registers per pass). s0 = first stage (0 or 2).
// ---------------------------------------------------------------------------
static __device__ __forceinline__ void fft_fwd_passes(float* z, const float2* tw,
                                                      int tid, int s0) {
    for (int s = s0; s < 6; s += 2) {
        const int hl = 10 - 2 * s;
        const int h  = 1 << hl;
        const int h4 = h >> 2;
        const int kk = tid & (h4 - 1);
        const int g  = tid >> (hl - 2);
        const int i0 = (g << (hl + 2)) + kk;     // g*4h + kk
        float2 e[4][4];
#pragma unroll
        for (int j = 0; j < 4; ++j)
#pragma unroll
            for (int r = 0; r < 4; ++r)
                e[j][r] = *(const float2*)&z[ZA(i0 + j * h4 + r * h)];
        // stage s: butterfly over r for each j; twiddle m = (kk + j*h4) << 2s
#pragma unroll
        for (int j = 0; j < 4; ++j) {
            float c1, s1, c2, s2, c3, s3;
            tw_derive(tw, (kk + j * h4) << (2 * s), c1, s1, c2, s2, c3, s3);
            bf_fwd(e[j][0], e[j][1], e[j][2], e[j][3], c1, s1, c2, s2, c3, s3);
        }
        // stage s+1: butterfly over j for each r; single twiddle set kk << (2s+2)
        {
            float c1, s1, c2, s2, c3, s3;
            tw_derive(tw, kk << (2 * s + 2), c1, s1, c2, s2, c3, s3);
#pragma unroll
            for (int r = 0; r < 4; ++r)
                bf_fwd(e[0][r], e[1][r], e[2][r], e[3][r], c1, s1, c2, s2, c3, s3);
        }
#pragma unroll
        for (int j = 0; j < 4; ++j)
#pragma unroll
            for (int r = 0; r < 4; ++r)
                *(float2*)&z[ZA(i0 + j * h4 + r * h)] = e[j][r];
        __syncthreads();
    }
}

// ---------------------------------------------------------------------------
// Sparse fused pass 1 (stages 0+1) for the corr signal: the only nonzero
// inputs in this thread's 16-element set are F = corr[tid] (j=0,r=0) and
// Tl = corr[3840+tid] (j=3,r=3), both in registers. Value-identical to the
// dense path; skips z zero/stage, 16 LDS reads, and one barrier.
// ---------------------------------------------------------------------------
static __device__ __forceinline__ void fft_fwd_pass1_sparse(
        float* z, const float2* tw, int tid, float2 F, float2 Tl) {
    float c1, s1, c2, s2, c3, s3;
    // stage 0, j=0 (twiddle m = tid)
    tw_derive(tw, tid, c1, s1, c2, s2, c3, s3);
    float2 P[4];
    P[0] = F;
    P[1] = cmul_em(F, c1, s1);
    P[2] = cmul_em(F, c2, s2);
    P[3] = cmul_em(F, c3, s3);
    // stage 0, j=3 (twiddle m = tid+768): inputs (0,0,0,Tl) -> u=(Tl, i*Tl, -Tl, -i*Tl)
    tw_derive(tw, tid + 768, c1, s1, c2, s2, c3, s3);
    const float2 iT  = make_float2(-Tl.y,  Tl.x);
    const float2 nT  = make_float2(-Tl.x, -Tl.y);
    const float2 niT = make_float2( Tl.y, -Tl.x);
    float2 Q[4];
    Q[0] = Tl;
    Q[1] = cmul_em(iT,  c1, s1);
    Q[2] = cmul_em(nT,  c2, s2);
    Q[3] = cmul_em(niT, c3, s3);
    // stage 1 (twiddle m = 4*tid): butterfly (P,0,0,Q) over j, per r
    tw_derive(tw, tid << 2, c1, s1, c2, s2, c3, s3);
#pragma unroll
    for (int r = 0; r < 4; ++r) {
        const int ib = tid + (r << 10);
        const float2 A = make_float2(P[r].x + Q[r].x, P[r].y + Q[r].y);
        const float2 B = cmul_em(make_float2(P[r].x - Q[r].y, P[r].y + Q[r].x), c1, s1); // P + iQ
        const float2 C = cmul_em(make_float2(P[r].x - Q[r].x, P[r].y - Q[r].y), c2, s2); // P - Q
        const float2 D = cmul_em(make_float2(P[r].x + Q[r].y, P[r].y - Q[r].x), c3, s3); // P - iQ
        *(float2*)&z[ZA(ib)]        = A;
        *(float2*)&z[ZA(ib + 256)]  = B;
        *(float2*)&z[ZA(ib + 512)]  = C;
        *(float2*)&z[ZA(ib + 768)]  = D;
    }
}

// ---------------------------------------------------------------------------
// Inverse radix-4 DIT, base-4 digit-reversed -> natural (unscaled), fused
// stage pairs.
// ---------------------------------------------------------------------------
static __device__ __forceinline__ void fft_inv6(float* z, const float2* tw, int tid) {
#pragma unroll
    for (int s = 0; s < 6; s += 2) {
        const int L  = 1 << (2 * s);
        const int k  = tid & (L - 1);
        const int g  = tid >> (2 * s);
        const int i0 = (g << (2 * s + 4)) + k;   // g*16L + k
        float2 e[4][4];
#pragma unroll
        for (int j = 0; j < 4; ++j)
#pragma unroll
            for (int r = 0; r < 4; ++r)
                e[j][r] = *(const float2*)&z[ZA(i0 + j * L + (r << (2 * s + 2)))];
        // stage s: butterfly over j for each r; single twiddle set k << (10-2s)
        {
            float c1, s1, c2, s2, c3, s3;
            tw_derive(tw, k << (10 - 2 * s), c1, s1, c2, s2, c3, s3);
#pragma unroll
            for (int r = 0; r < 4; ++r)
                bf_inv(e[0][r], e[1][r], e[2][r], e[3][r], c1, s1, c2, s2, c3, s3);
        }
        // stage s+1: butterfly over r for each j; twiddle (k + j*L) << (8-2s)
#pragma unroll
        for (int j = 0; j < 4; ++j) {
            float c1, s1, c2, s2, c3, s3;
            tw_derive(tw, (k + j * L) << (8 - 2 * s), c1, s1, c2, s2, c3, s3);
            bf_inv(e[j][0], e[j][1], e[j][2], e[j][3], c1, s1, c2, s2, c3, s3);
        }
#pragma unroll
        for (int j = 0; j < 4; ++j)
#pragma unroll
            for (int r = 0; r < 4; ++r)
                *(float2*)&z[ZA(i0 + j * L + (r << (2 * s + 2)))] = e[j][r];
        __syncthreads();
    }
}

// ---------------------------------------------------------------------------
// spectral_pre: blocks 0..63 -> X[bc]; 64..83 -> Hf[band]; 84 -> twiddle
// writer; 85..596 (when do_corr) -> boundary-correction values for all
// (bc, band, t) hoisted out of spectral_main. corr blocks use the SAME fp32
// fmaf chains (same order, same staged xe values) -> bitwise-identical.
// smem: FFT branch: z[8704] | twl[1024 f2] | fb[513]. corr branch: xe[512] |
// fbs[20*513] (overlaid). 45060 B -> 3 blocks/CU; 597 blocks fit one round.
// ---------------------------------------------------------------------------
__global__ __launch_bounds__(256) void spectral_pre(
    const float* __restrict__ x,      // (BC, T)
    const float* __restrict__ filt,   // (20, 513)
    float2* __restrict__ Xs,          // (BC, 4096)
    float2* __restrict__ Hs,          // (20, 4096)
    float* __restrict__ corr)         // (BC, 20, 2, 256) or null
{
    __shared__ __align__(16) float sm[11265];

    const int tid = threadIdx.x;
    const int b   = blockIdx.x;

    if (b == BC + N_BANDS) {          // twiddle-table writer
        for (int m = tid; m < 1024; m += 256) {
            float ang = (float)m * (6.283185307179586f / 4096.0f);
            float s, c;
            sincosf(ang, &s, &c);
            twg_dev[m] = make_float2(c, s);
        }
        return;
    }

    if (b > BC + N_BANDS) {
        // ---- corr blocks: cidx = b-85; bc = cidx>>3; oct = cidx&7
        const int cidx = b - (BC + N_BANDS + 1);
        const int bc   = cidx >> 3;
        const int oct  = cidx & 7;
        float* xe  = sm;          // 512
        float* fbs = sm + 512;    // 20*513 = 10260

        const float* xrow = x + bc * T_LEN;
        for (int i = tid; i < 512; i += 256)
            xe[i] = (i < 256) ? xrow[i] : xrow[3584 + i];
        for (int i = tid; i < N_BANDS * FIR_L; i += 256)
            fbs[i] = filt[i];
        __syncthreads();

        const int tl = tid & 31;
        const int bg = (tid >> 5) & 3;      // band group (5 bands each)
        const int t  = oct * 32 + tl;       // t in [0,256)
        if (tid < 128) {
            // front: cf[t] = sum_{l=0}^{255-t} f[l] * xe[256+t+l]
#pragma unroll 1
            for (int b5 = 0; b5 < 5; ++b5) {
                const int band = bg * 5 + b5;
                const float* fbp = fbs + band * FIR_L;
                float cf = 0.0f;
                for (int l = 0; l <= 255 - t; ++l)
                    cf = fmaf(fbp[l], xe[256 + t + l], cf);
                corr[((bc * N_BANDS + band) * 2 + 0) * 256 + t] = cf;
            }
        } else {
            // tail: ct[t] = sum_{j=0}^{t} f[512-t+j] * xe[j]
#pragma unroll 1
            for (int b5 = 0; b5 < 5; ++b5) {
                const int band = bg * 5 + b5;
                const float* fbp = fbs + band * FIR_L;
                float ct = 0.0f;
                for (int j = 0; j <= t; ++j)
                    ct = fmaf(fbp[512 - t + j], xe[j], ct);
                corr[((bc * N_BANDS + band) * 2 + 1) * 256 + t] = ct;
            }
        }
        return;
    }

    // ---- FFT blocks (verbatim R2)
    float*  z   = sm;
    float2* twl = (float2*)(sm + 8704);
    float*  fb  = sm + 8704 + 2048;

    for (int m = tid; m < 1024; m += 256) {
        float ang = (float)m * (6.283185307179586f / 4096.0f);
        float s, c;
        sincosf(ang, &s, &c);
        twl[m] = make_float2(c, s);
    }

    if (b < BC) {
        const float* xrow = x + b * T_LEN;
        for (int i = tid; i < 4096; i += 256)
            *(float2*)&z[ZA(i)] = make_float2(xrow[i], 0.0f);
    } else {
        const int band = b - BC;
        for (int i = tid; i < FIR_L; i += 256) fb[i] = filt[band * FIR_L + i];
        __syncthreads();
        // h[n] = f[256-n] for n in [0,257); h[n] = f[4352-n] for n in [3840,4096)
        for (int i = tid; i < 4096; i += 256) {
            float hv = 0.0f;
            if (i < 257)        hv = fb[256 - i];
            else if (i >= 3840) hv = fb[4352 - i];
            *(float2*)&z[ZA(i)] = make_float2(hv, 0.0f);
        }
    }
    __syncthreads();

    fft_fwd_passes(z, twl, tid, 0);

    float2* dst = (b < BC) ? (Xs + b * 4096) : (Hs + (b - BC) * 4096);
    for (int i = tid; i < 4096; i += 256)
        dst[i] = *(const float2*)&z[ZA(i)];
}

// ---------------------------------------------------------------------------
// Fast main: corr precomputed -> per unit just 2 coalesced loads; no xe/fb
// staging, no corr loops, one fewer barrier. LDS = z only (34816 B, 4/CU).
// ---------------------------------------------------------------------------
__global__ __launch_bounds__(256, 4) void spectral_main_pre(
    const float* __restrict__ corr,       // (BC, 20, 2, 256)
    const float2* __restrict__ Xs,        // (BC, 4096)
    const float2* __restrict__ Hs,        // (20, 4096)
    float* __restrict__ pha,              // (BC, 10, T) fp32
    unsigned short* __restrict__ amp_bf)  // (BC, 10, T) bf16 bits
{
    __shared__ __align__(16) float z[8704];   // 34816 B

    const int tid  = threadIdx.x;
    const int bc   = blockIdx.x / N_BANDS;
    const int band = blockIdx.x % N_BANDS;
    const float2* tw = twg_dev;

    const float cf = corr[((bc * N_BANDS + band) * 2 + 0) * 256 + tid];
    const float ct = corr[((bc * N_BANDS + band) * 2 + 1) * 256 + tid];

    // ---- fwd FFT of corr: sparse pass 1 from registers, then dense passes
    fft_fwd_pass1_sparse(z, tw, tid, make_float2(-cf, 0.0f), make_float2(-ct, 0.0f));
    __syncthreads();
    fft_fwd_passes(z, tw, tid, 2);    // passes s=2,4

    // ---- pointwise: P = X*Hf + C, Hilbert mask, back into z
    const float2* Xrow = Xs + bc * 4096;
    const float2* Hrow = Hs + band * 4096;
    for (int i = tid; i < 4096; i += 256) {
        const float2 X = Xrow[i];
        const float2 H = Hrow[i];
        const float2 C = *(const float2*)&z[ZA(i)];
        float pr = X.x * H.x - X.y * H.y + C.x;
        float pi = X.x * H.y + X.y * H.x + C.y;
        const int f = digitrev12(i);
        const float mf = (f == 0 || f == 2048) ? 1.0f : (f < 2048 ? 2.0f : 0.0f);
        *(float2*)&z[ZA(i)] = make_float2(pr * mf, pi * mf);
    }
    __syncthreads();

    fft_inv6(z, tw, tid);    // analytic signal (unscaled by 1/N)

    // ---- emit phase (fp32) or amplitude (bf16)
    const float inv_n = 1.0f / 4096.0f;
    if (band < N_PHA) {
        float* dst = pha + (bc * N_PHA + band) * T_LEN;
        for (int i = tid; i < 4096; i += 256) {
            const float2 zz = *(const float2*)&z[ZA(i)];
            dst[i] = atan2f(zz.y, zz.x);         // scale cancels in atan2
        }
    } else {
        unsigned short* dst = amp_bf + (bc * N_AMP + (band - N_PHA)) * T_LEN;
        for (int i = tid; i < 4096; i += 256) {
            const float2 zz = *(const float2*)&z[ZA(i)];
            dst[i] = f2bf(sqrtf(zz.x * zz.x + zz.y * zz.y) * inv_n);
        }
    }
}

// ---------------------------------------------------------------------------
// Fallback main (verbatim R2): inline corr loops. Used only if ws too small.
// ---------------------------------------------------------------------------
__global__ __launch_bounds__(256, 4) void spectral_main_inline(
    const float* __restrict__ x,          // (BC, T)
    const float* __restrict__ filt,       // (20, 513)
    const float2* __restrict__ Xs,        // (BC, 4096)
    const float2* __restrict__ Hs,        // (20, 4096)
    float* __restrict__ pha,              // (BC, 10, T) fp32
    unsigned short* __restrict__ amp_bf)  // (BC, 10, T) bf16 bits
{
    __shared__ float z[8704];
    __shared__ float xe[512];
    __shared__ float fb[FIR_L];

    const int tid  = threadIdx.x;
    const int bc   = blockIdx.x / N_BANDS;
    const int band = blockIdx.x % N_BANDS;
    const float2* tw = twg_dev;

    const float* xrow = x + bc * T_LEN;
    for (int i = tid; i < 512; i += 256)
        xe[i] = (i < 256) ? xrow[i] : xrow[3584 + i];
    for (int i = tid; i < FIR_L; i += 256) fb[i] = filt[band * FIR_L + i];
    __syncthreads();

    float cf = 0.0f, ct = 0.0f;
    for (int l = 0; l <= 255 - tid; ++l)
        cf = fmaf(fb[l], xe[256 + tid + l], cf);
    for (int j = 0; j <= tid; ++j)
        ct = fmaf(fb[512 - tid + j], xe[j], ct);

    fft_fwd_pass1_sparse(z, tw, tid, make_float2(-cf, 0.0f), make_float2(-ct, 0.0f));
    __syncthreads();
    fft_fwd_passes(z, tw, tid, 2);

    const float2* Xrow = Xs + bc * 4096;
    const float2* Hrow = Hs + band * 4096;
    for (int i = tid; i < 4096; i += 256) {
        const float2 X = Xrow[i];
        const float2 H = Hrow[i];
        const float2 C = *(const float2*)&z[ZA(i)];
        float pr = X.x * H.x - X.y * H.y + C.x;
        float pi = X.x * H.y + X.y * H.x + C.y;
        const int f = digitrev12(i);
        const float mf = (f == 0 || f == 2048) ? 1.0f : (f < 2048 ? 2.0f : 0.0f);
        *(float2*)&z[ZA(i)] = make_float2(pr * mf, pi * mf);
    }
    __syncthreads();

    fft_inv6(z, tw, tid);

    const float inv_n = 1.0f / 4096.0f;
    if (band < N_PHA) {
        float* dst = pha + (bc * N_PHA + band) * T_LEN;
        for (int i = tid; i < 4096; i += 256) {
            const float2 zz = *(const float2*)&z[ZA(i)];
            dst[i] = atan2f(zz.y, zz.x);
        }
    } else {
        unsigned short* dst = amp_bf + (bc * N_AMP + (band - N_PHA)) * T_LEN;
        for (int i = tid; i < 4096; i += 256) {
            const float2 zz = *(const float2*)&z[ZA(i)];
            dst[i] = f2bf(sqrtf(zz.x * zz.x + zz.y * zz.y) * inv_n);
        }
    }
}

// ---------------------------------------------------------------------------
// Kernel 2: per (bc, pha-band): 3-hot soft phase binning + einsum via MFMA.
// 512 threads / 8 waves per block (verbatim R2).
// ---------------------------------------------------------------------------
__global__ __launch_bounds__(512) void bin_mi_mfma(
    const float* __restrict__ pha,             // (BC, 10, T) fp32
    const unsigned short* __restrict__ amp_bf, // (BC, 10, T) bf16 bits
    float* __restrict__ out)                   // (BC, 10, 10)
{
    const int tid  = threadIdx.x;
    const int lane = tid & 63;
    const int wv   = tid >> 6;        // 0..7
    const int bc   = blockIdx.x / N_PHA;
    const int p    = blockIdx.x % N_PHA;

    __shared__ unsigned int wbufW[8][18 * 68];
    __shared__ float psum[8][11][N_BINS];
    __shared__ float asum[11][N_BINS];

    const float* phrow = pha + (bc * N_PHA + p) * T_LEN;
    const unsigned short* arow = amp_bf + bc * N_AMP * T_LEN;

    const float PI_F  = 3.14159274101257324f;
    const float INVD  = 2.8647889756541160f;   // 9/pi
    const float DELTA = 0.34906585039886590f;  // 2pi/18
    const float C1    = 12.184696791468343f;   // DELTA^2 / 0.01
    const float C2    = 69.813170079773180f;   // 2*DELTA / 0.01

    const int m_ = lane & 15;
    const int q_ = lane >> 4;
    const int n_ = lane & 15;

    short8 zero8;
#pragma unroll
    for (int j = 0; j < 8; ++j) zero8[j] = 0;
    short8 ones8;
#pragma unroll
    for (int j = 0; j < 8; ++j) ones8[j] = (short)0x3F80;   // bf16 1.0

    f32x4 acc0 = {0.f, 0.f, 0.f, 0.f};   // bins 0..15
    f32x4 acc1 = {0.f, 0.f, 0.f, 0.f};   // bins 16..17

    const int base_t = wv * 512;
    unsigned short* wh = (unsigned short*)&wbufW[wv][0];

    float2 pp[4];
#pragma unroll
    for (int c = 0; c < 4; ++c)
        pp[c] = *(const float2*)&phrow[base_t + c * 128 + lane * 2];

    for (int chunk = 0; chunk < 4; ++chunk) {
        const int cb = base_t + chunk * 128;

        short8 af[4];
#pragma unroll
        for (int s = 0; s < 4; ++s) {
            const int tA = cb + s * 32 + q_ * 8;
            if (m_ < N_AMP)       af[s] = *(const short8*)(arow + m_ * T_LEN + tA);
            else if (m_ == N_AMP) af[s] = ones8;
            else                  af[s] = zero8;
        }

#pragma unroll
        for (int k = 0; k < N_BINS; ++k)
            wbufW[wv][k * 68 + lane] = 0u;

#pragma unroll
        for (int h = 0; h < 2; ++h) {
            const float ph = h ? pp[chunk].y : pp[chunk].x;
            float u  = (ph + PI_F) * INVD;       // in [0, 18]
            float jf = floorf(u);
            float d  = (u - jf - 0.5f) * DELTA;
            int j0 = (int)jf;
            if (j0 >= N_BINS) j0 -= N_BINS;      // ph == +pi wraps
            const int jm = (j0 == 0) ? N_BINS - 1 : j0 - 1;
            const int jp = (j0 == N_BINS - 1) ? 0 : j0 + 1;
            const float em = expf(-C1 - C2 * d);
            const float ep = expf(-C1 + C2 * d);
            const float inv = 1.0f / (1.0f + em + ep);
            wh[(j0 * 68 + lane) * 2 + h] = f2bf(inv);
            wh[(jm * 68 + lane) * 2 + h] = f2bf(em * inv);
            wh[(jp * 68 + lane) * 2 + h] = f2bf(ep * inv);
        }
        __builtin_amdgcn_wave_barrier();

#pragma unroll
        for (int s = 0; s < 4; ++s) {
            const int woff = s * 16 + q_ * 4;
            short8 bfrag0 = *(const short8*)&wbufW[wv][n_ * 68 + woff];
            short8 bfrag1 = (n_ < 2)
                ? *(const short8*)&wbufW[wv][(16 + n_) * 68 + woff]
                : zero8;
            acc0 = __builtin_amdgcn_mfma_f32_16x16x32_bf16(af[s], bfrag0, acc0, 0, 0, 0);
            acc1 = __builtin_amdgcn_mfma_f32_16x16x32_bf16(af[s], bfrag1, acc1, 0, 0, 0);
        }
        __builtin_amdgcn_wave_barrier();
    }

#pragma unroll
    for (int r = 0; r < 4; ++r) {
        const int m = q_ * 4 + r;
        if (m < 11) {
            psum[wv][m][n_] = acc0[r];
            if (n_ < 2) psum[wv][m][16 + n_] = acc1[r];
        }
    }
    __syncthreads();

    if (tid < 11 * N_BINS) {
        const int m = tid / N_BINS;
        const int k = tid % N_BINS;
        float s = 0.0f;
#pragma unroll
        for (int w = 0; w < 8; ++w) s += psum[w][m][k];
        asum[m][k] = s;
    }
    __syncthreads();

    if (tid < N_AMP) {
        float ma[N_BINS];
        float msum = 0.0f;
#pragma unroll
        for (int k = 0; k < N_BINS; ++k) {
            float m = asum[tid][k] / (asum[10][k] + 1e-8f);
            ma[k] = m;
            msum += m;
        }
        const float inv = 1.0f / (msum + 1e-8f);
        float acc = 0.0f;
#pragma unroll
        for (int k = 0; k < N_BINS; ++k) {
            float pk = ma[k] * inv;
            acc = fmaf(pk, logf(pk + 1e-8f), acc);
        }
        const float logk = 2.89037175789124f;    // log(18)
        out[(bc * N_PHA + p) * N_AMP + tid] = (logk + acc) / logk;
    }
}

extern "C" void kernel_launch(void* const* d_in, const int* in_sizes, int n_in,
                              void* d_out, int out_size, void* d_ws, size_t ws_size,
                              hipStream_t stream) {
    const float* x    = (const float*)d_in[0];   // (4,16,4096) f32
    const float* filt = (const float*)d_in[1];   // (20,513) f32
    float* out = (float*)d_out;                  // (4,16,10,10) f32

    // ws layout: pha fp32 | amp bf16 | Xspec | Hspec | corr  (~21.1 MB)
    float* pha = (float*)d_ws;                               // BC*10*T fp32
    unsigned short* amp_bf = (unsigned short*)(pha + BC * N_PHA * T_LEN);
    float2* Xs = (float2*)(amp_bf + BC * N_AMP * T_LEN);     // BC*4096 cplx
    float2* Hs = Xs + BC * 4096;                             // 20*4096 cplx
    float* corr = (float*)(Hs + N_BANDS * 4096);             // BC*20*2*256 f32

    const size_t need = (size_t)BC * N_PHA * T_LEN * 4
                      + (size_t)BC * N_AMP * T_LEN * 2
                      + (size_t)BC * 4096 * 8
                      + (size_t)N_BANDS * 4096 * 8
                      + (size_t)BC * N_BANDS * 2 * 256 * 4;   // 21,102,592
    const bool fits = (ws_size >= need);

    if (fits) {
        spectral_pre<<<BC + N_BANDS + 1 + 512, 256, 0, stream>>>(x, filt, Xs, Hs, corr);
        spectral_main_pre<<<BC * N_BANDS, 256, 0, stream>>>(corr, Xs, Hs, pha, amp_bf);
    } else {
        spectral_pre<<<BC + N_BANDS + 1, 256, 0, stream>>>(x, filt, Xs, Hs, corr);
        spectral_main_inline<<<BC * N_BANDS, 256, 0, stream>>>(x, filt, Xs, Hs, pha, amp_bf);
    }
    bin_mi_mfma<<<BC * N_PHA, 512, 0, stream>>>(pha, amp_bf, out);
}

// Round 6
// 114.686 us; speedup vs baseline: 2.4783x; 1.0632x over previous
//
#include <hip/hip_runtime.h>
#include <math.h>

// Problem constants (match reference)
#define T_LEN 4096
#define FIR_L 513
#define N_PHA 10
#define N_AMP 10
#define N_BANDS 20
#define N_BINS 18
#define BC 64            // B*C = 4*16

typedef __attribute__((ext_vector_type(8))) short short8;
typedef __attribute__((ext_vector_type(4))) float f32x4;

// Interleaved-complex skewed addresses for z (float index of re; im at +1).
// Even skew keeps 8-byte alignment for b64 LDS ops.
// Extent: ZA(4095)+2 = 8702 -> z region 8704 floats.
#define ZA(i) (((i) << 1) + ((((i) >> 4)) << 1))

// Global twiddle table (1024 complex), written by spectral_pre's block 84
// with the same libm sincosf values as always -> bitwise-identical FFTs.
__device__ float2 twg_dev[1024];

// float -> bf16 round-to-nearest-even
static __device__ __forceinline__ unsigned short f2bf(float x) {
    unsigned u = __float_as_uint(x);
    unsigned r = u + 0x7FFFu + ((u >> 16) & 1u);
    return (unsigned short)(r >> 16);
}

// Fast atan2 (cephes atanf reduction + deg-9 minimax, ~2e-7 rad max err,
// single division). Phase error propagates to MI output at <1e-5 abs
// (threshold 7.6e-5). Sign-of-zero / (0,0) corner cases are measure-zero
// under the random-normal input and benign for circular binning.
static __device__ __forceinline__ float fast_atan2f(float y, float x) {
    const float ax = fabsf(x), ay = fabsf(y);
    const float mx = fmaxf(ax, ay), mn = fminf(ax, ay);
    const bool swap = ay > ax;
    const bool red  = mn > 0.4142135623730950f * mx;   // t > tan(pi/8)
    const float num = red ? (mn - mx) : mn;
    const float den = red ? (mn + mx) : mx;
    const float u  = num / den;                        // in (-0.4142, 1]... reduced
    const float z2 = u * u;
    float p = fmaf(8.05374449538e-2f, z2, -1.38776856032e-1f);
    p = fmaf(p, z2, 1.99777106478e-1f);
    p = fmaf(p, z2, -3.33329491539e-1f);
    float a = fmaf(p * z2, u, u);
    if (red)  a += 0.7853981633974483f;                // + pi/4
    if (swap) a = 1.5707963267948966f - a;
    if (x < 0.0f) a = 3.14159265358979323f - a;
    return (y < 0.0f) ? -a : a;
}

// twiddle fetch + double/sum-angle derivation
static __device__ __forceinline__ void tw_derive(const float2* tw, int m1,
        float& c1, float& s1, float& c2, float& s2, float& c3, float& s3) {
    const float2 w1 = tw[m1];
    c1 = w1.x; s1 = w1.y;
    s2 = 2.0f * s1 * c1;                 // double angle
    c2 = fmaf(-2.0f * s1, s1, 1.0f);
    c3 = c1 * c2 - s1 * s2;              // angle sum
    s3 = s1 * c2 + c1 * s2;
}

// u * e^{-i theta}, theta given as (c, s)
static __device__ __forceinline__ float2 cmul_em(float2 u, float c, float s) {
    return make_float2(u.x * c + u.y * s, u.y * c - u.x * s);
}

// forward radix-4 DIF butterfly (multiply by e^{-i theta})
static __device__ __forceinline__ void bf_fwd(float2& A, float2& B, float2& C, float2& D,
        float c1, float s1, float c2, float s2, float c3, float s3) {
    const float t0r = A.x + C.x, t0i = A.y + C.y;
    const float t1r = A.x - C.x, t1i = A.y - C.y;
    const float t2r = B.x + D.x, t2i = B.y + D.y;
    const float t3r = B.x - D.x, t3i = B.y - D.y;
    const float y0r = t0r + t2r,  y0i = t0i + t2i;
    const float u1r = t1r + t3i, u1i = t1i - t3r;   // t1 - i*t3
    const float u2r = t0r - t2r, u2i = t0i - t2i;
    const float u3r = t1r - t3i, u3i = t1i + t3r;   // t1 + i*t3
    A = make_float2(y0r, y0i);
    B = make_float2(u1r * c1 + u1i * s1, u1i * c1 - u1r * s1);
    C = make_float2(u2r * c2 + u2i * s2, u2i * c2 - u2r * s2);
    D = make_float2(u3r * c3 + u3i * s3, u3i * c3 - u3r * s3);
}

// inverse radix-4 DIT butterfly (multiply by e^{+i theta})
static __device__ __forceinline__ void bf_inv(float2& A, float2& B, float2& C, float2& D,
        float c1, float s1, float c2, float s2, float c3, float s3) {
    const float tbr = B.x * c1 - B.y * s1, tbi = B.y * c1 + B.x * s1;
    const float tcr = C.x * c2 - C.y * s2, tci = C.y * c2 + C.x * s2;
    const float tdr = D.x * c3 - D.y * s3, tdi = D.y * c3 + D.x * s3;
    const float ar = A.x, ai = A.y;
    A = make_float2(ar + tbr + tcr + tdr, ai + tbi + tci + tdi);
    B = make_float2(ar - tbi - tcr + tdi, ai + tbr - tci - tdr);   // a + i*tb - tc - i*td
    C = make_float2(ar - tbr + tcr - tdr, ai - tbi + tci - tdi);
    D = make_float2(ar + tbi - tcr - tdi, ai - tbr - tci + tdr);   // a - i*tb - tc + i*td
}

// ---------------------------------------------------------------------------
// Forward radix-4 DIF, natural -> base-4 digit-reversed, fused stage pairs
// (16 elements/thread in registers per pass). s0 = first stage (0 or 2).
// ---------------------------------------------------------------------------
static __device__ __forceinline__ void fft_fwd_passes(float* z, const float2* tw,
                                                      int tid, int s0) {
    for (int s = s0; s < 6; s += 2) {
        const int hl = 10 - 2 * s;
        const int h  = 1 << hl;
        const int h4 = h >> 2;
        const int kk = tid & (h4 - 1);
        const int g  = tid >> (hl - 2);
        const int i0 = (g << (hl + 2)) + kk;     // g*4h + kk
        float2 e[4][4];
#pragma unroll
        for (int j = 0; j < 4; ++j)
#pragma unroll
            for (int r = 0; r < 4; ++r)
                e[j][r] = *(const float2*)&z[ZA(i0 + j * h4 + r * h)];
        // stage s: butterfly over r for each j; twiddle m = (kk + j*h4) << 2s
#pragma unroll
        for (int j = 0; j < 4; ++j) {
            float c1, s1, c2, s2, c3, s3;
            tw_derive(tw, (kk + j * h4) << (2 * s), c1, s1, c2, s2, c3, s3);
            bf_fwd(e[j][0], e[j][1], e[j][2], e[j][3], c1, s1, c2, s2, c3, s3);
        }
        // stage s+1: butterfly over j for each r; single twiddle set kk << (2s+2)
        {
            float c1, s1, c2, s2, c3, s3;
            tw_derive(tw, kk << (2 * s + 2), c1, s1, c2, s2, c3, s3);
#pragma unroll
            for (int r = 0; r < 4; ++r)
                bf_fwd(e[0][r], e[1][r], e[2][r], e[3][r], c1, s1, c2, s2, c3, s3);
        }
#pragma unroll
        for (int j = 0; j < 4; ++j)
#pragma unroll
            for (int r = 0; r < 4; ++r)
                *(float2*)&z[ZA(i0 + j * h4 + r * h)] = e[j][r];
        __syncthreads();
    }
}

// ---------------------------------------------------------------------------
// Sparse fused pass 1 (stages 0+1) for the corr signal: the only nonzero
// inputs in this thread's 16-element set are F = corr[tid] (j=0,r=0) and
// Tl = corr[3840+tid] (j=3,r=3), both in registers. Value-identical to the
// dense path; skips z zero/stage, 16 LDS reads, and one barrier.
// ---------------------------------------------------------------------------
static __device__ __forceinline__ void fft_fwd_pass1_sparse(
        float* z, const float2* tw, int tid, float2 F, float2 Tl) {
    float c1, s1, c2, s2, c3, s3;
    // stage 0, j=0 (twiddle m = tid)
    tw_derive(tw, tid, c1, s1, c2, s2, c3, s3);
    float2 P[4];
    P[0] = F;
    P[1] = cmul_em(F, c1, s1);
    P[2] = cmul_em(F, c2, s2);
    P[3] = cmul_em(F, c3, s3);
    // stage 0, j=3 (twiddle m = tid+768): inputs (0,0,0,Tl) -> u=(Tl, i*Tl, -Tl, -i*Tl)
    tw_derive(tw, tid + 768, c1, s1, c2, s2, c3, s3);
    const float2 iT  = make_float2(-Tl.y,  Tl.x);
    const float2 nT  = make_float2(-Tl.x, -Tl.y);
    const float2 niT = make_float2( Tl.y, -Tl.x);
    float2 Q[4];
    Q[0] = Tl;
    Q[1] = cmul_em(iT,  c1, s1);
    Q[2] = cmul_em(nT,  c2, s2);
    Q[3] = cmul_em(niT, c3, s3);
    // stage 1 (twiddle m = 4*tid): butterfly (P,0,0,Q) over j, per r
    tw_derive(tw, tid << 2, c1, s1, c2, s2, c3, s3);
#pragma unroll
    for (int r = 0; r < 4; ++r) {
        const int ib = tid + (r << 10);
        const float2 A = make_float2(P[r].x + Q[r].x, P[r].y + Q[r].y);
        const float2 B = cmul_em(make_float2(P[r].x - Q[r].y, P[r].y + Q[r].x), c1, s1); // P + iQ
        const float2 C = cmul_em(make_float2(P[r].x - Q[r].x, P[r].y - Q[r].y), c2, s2); // P - Q
        const float2 D = cmul_em(make_float2(P[r].x + Q[r].y, P[r].y - Q[r].x), c3, s3); // P - iQ
        *(float2*)&z[ZA(ib)]        = A;
        *(float2*)&z[ZA(ib + 256)]  = B;
        *(float2*)&z[ZA(ib + 512)]  = C;
        *(float2*)&z[ZA(ib + 768)]  = D;
    }
}

// ---------------------------------------------------------------------------
// Inverse radix-4 DIT, base-4 digit-reversed -> natural (unscaled), fused
// stage pairs.
// ---------------------------------------------------------------------------
static __device__ __forceinline__ void fft_inv6(float* z, const float2* tw, int tid) {
#pragma unroll
    for (int s = 0; s < 6; s += 2) {
        const int L  = 1 << (2 * s);
        const int k  = tid & (L - 1);
        const int g  = tid >> (2 * s);
        const int i0 = (g << (2 * s + 4)) + k;   // g*16L + k
        float2 e[4][4];
#pragma unroll
        for (int j = 0; j < 4; ++j)
#pragma unroll
            for (int r = 0; r < 4; ++r)
                e[j][r] = *(const float2*)&z[ZA(i0 + j * L + (r << (2 * s + 2)))];
        // stage s: butterfly over j for each r; single twiddle set k << (10-2s)
        {
            float c1, s1, c2, s2, c3, s3;
            tw_derive(tw, k << (10 - 2 * s), c1, s1, c2, s2, c3, s3);
#pragma unroll
            for (int r = 0; r < 4; ++r)
                bf_inv(e[0][r], e[1][r], e[2][r], e[3][r], c1, s1, c2, s2, c3, s3);
        }
        // stage s+1: butterfly over r for each j; twiddle (k + j*L) << (8-2s)
#pragma unroll
        for (int j = 0; j < 4; ++j) {
            float c1, s1, c2, s2, c3, s3;
            tw_derive(tw, (k + j * L) << (8 - 2 * s), c1, s1, c2, s2, c3, s3);
            bf_inv(e[j][0], e[j][1], e[j][2], e[j][3], c1, s1, c2, s2, c3, s3);
        }
#pragma unroll
        for (int j = 0; j < 4; ++j)
#pragma unroll
            for (int r = 0; r < 4; ++r)
                *(float2*)&z[ZA(i0 + j * L + (r << (2 * s + 2)))] = e[j][r];
        __syncthreads();
    }
}

// ---------------------------------------------------------------------------
// spectral_pre: blocks 0..63 -> X[bc]; 64..83 -> Hf[band]; 84 -> twiddle
// writer; 85..1364 -> corr for ONE (bc, band) each: every thread runs the
// SAME balanced 257-FMA chains as the old inline main (bitwise-identical),
// so corr cost is one chain deep instead of 5 serial bands (R5 imbalance).
// ---------------------------------------------------------------------------
__global__ __launch_bounds__(256) void spectral_pre(
    const float* __restrict__ x,      // (BC, T)
    const float* __restrict__ filt,   // (20, 513)
    float2* __restrict__ Xs,          // (BC, 4096)
    float2* __restrict__ Hs,          // (20, 4096)
    float* __restrict__ corr)         // (BC, 20, 2, 256)
{
    __shared__ __align__(16) float sm[11265];

    const int tid = threadIdx.x;
    const int b   = blockIdx.x;

    if (b == BC + N_BANDS) {          // twiddle-table writer
        for (int m = tid; m < 1024; m += 256) {
            float ang = (float)m * (6.283185307179586f / 4096.0f);
            float s, c;
            sincosf(ang, &s, &c);
            twg_dev[m] = make_float2(c, s);
        }
        return;
    }

    if (b > BC + N_BANDS) {
        // ---- corr blocks: one (bc, band) each; balanced 257 FMAs/thread
        const int cidx = b - (BC + N_BANDS + 1);
        const int bc   = cidx / N_BANDS;
        const int band = cidx % N_BANDS;
        float* xe = sm;          // 512
        float* fb = sm + 512;    // 513

        const float* xrow = x + bc * T_LEN;
        for (int i = tid; i < 512; i += 256)
            xe[i] = (i < 256) ? xrow[i] : xrow[3584 + i];
        for (int i = tid; i < FIR_L; i += 256)
            fb[i] = filt[band * FIR_L + i];
        __syncthreads();

        const int t = tid;
        float cf = 0.0f, ct = 0.0f;
        for (int l = 0; l <= 255 - t; ++l)
            cf = fmaf(fb[l], xe[256 + t + l], cf);
        for (int j = 0; j <= t; ++j)
            ct = fmaf(fb[512 - t + j], xe[j], ct);

        corr[((bc * N_BANDS + band) * 2 + 0) * 256 + t] = cf;
        corr[((bc * N_BANDS + band) * 2 + 1) * 256 + t] = ct;
        return;
    }

    // ---- FFT blocks (verbatim R2)
    float*  z   = sm;
    float2* twl = (float2*)(sm + 8704);
    float*  fb  = sm + 8704 + 2048;

    for (int m = tid; m < 1024; m += 256) {
        float ang = (float)m * (6.283185307179586f / 4096.0f);
        float s, c;
        sincosf(ang, &s, &c);
        twl[m] = make_float2(c, s);
    }

    if (b < BC) {
        const float* xrow = x + b * T_LEN;
        for (int i = tid; i < 4096; i += 256)
            *(float2*)&z[ZA(i)] = make_float2(xrow[i], 0.0f);
    } else {
        const int band = b - BC;
        for (int i = tid; i < FIR_L; i += 256) fb[i] = filt[band * FIR_L + i];
        __syncthreads();
        // h[n] = f[256-n] for n in [0,257); h[n] = f[4352-n] for n in [3840,4096)
        for (int i = tid; i < 4096; i += 256) {
            float hv = 0.0f;
            if (i < 257)        hv = fb[256 - i];
            else if (i >= 3840) hv = fb[4352 - i];
            *(float2*)&z[ZA(i)] = make_float2(hv, 0.0f);
        }
    }
    __syncthreads();

    fft_fwd_passes(z, twl, tid, 0);

    float2* dst = (b < BC) ? (Xs + b * 4096) : (Hs + (b - BC) * 4096);
    for (int i = tid; i < 4096; i += 256)
        dst[i] = *(const float2*)&z[ZA(i)];
}

// ---------------------------------------------------------------------------
// Fast main. Pointwise exploits the Hilbert-mask structure in storage order:
// mf = 0 exactly at p%4 in {2,3} except p==2 (since freq = base-4 digit
// reversal of p: f>=2048 <=> p%4>=2, f==2048 <=> p==2). So: compute only the
// 2048 nonzero slots (8 iters/thread), zero-store the rest, and drop
// digitrev12 entirely. Phase emit uses fast_atan2f.
// ---------------------------------------------------------------------------
__global__ __launch_bounds__(256, 4) void spectral_main_pre(
    const float* __restrict__ corr,       // (BC, 20, 2, 256)
    const float2* __restrict__ Xs,        // (BC, 4096)
    const float2* __restrict__ Hs,        // (20, 4096)
    float* __restrict__ pha,              // (BC, 10, T) fp32
    unsigned short* __restrict__ amp_bf)  // (BC, 10, T) bf16 bits
{
    __shared__ __align__(16) float z[8704];   // 34816 B -> 4 blocks/CU

    const int tid  = threadIdx.x;
    const int bc   = blockIdx.x / N_BANDS;
    const int band = blockIdx.x % N_BANDS;
    const float2* tw = twg_dev;

    const float cf = corr[((bc * N_BANDS + band) * 2 + 0) * 256 + tid];
    const float ct = corr[((bc * N_BANDS + band) * 2 + 1) * 256 + tid];

    // ---- fwd FFT of corr: sparse pass 1 from registers, then dense passes
    fft_fwd_pass1_sparse(z, tw, tid, make_float2(-cf, 0.0f), make_float2(-ct, 0.0f));
    __syncthreads();
    fft_fwd_passes(z, tw, tid, 2);    // passes s=2,4

    // ---- pointwise P = X*Hf + C with mask, masked-half skipped
    const float2* Xrow = Xs + bc * 4096;
    const float2* Hrow = Hs + band * 4096;
    // nonzero slots: i = 4*(s>>1) + (s&1)  (p%4 in {0,1})
#pragma unroll
    for (int k = 0; k < 8; ++k) {
        const int s = tid + (k << 8);
        const int i = ((s >> 1) << 2) | (s & 1);
        const float2 X = Xrow[i];
        const float2 H = Hrow[i];
        const float2 C = *(const float2*)&z[ZA(i)];
        const float pr = X.x * H.x - X.y * H.y + C.x;
        const float pi = X.x * H.y + X.y * H.x + C.y;
        const float mf = (i == 0) ? 1.0f : 2.0f;
        *(float2*)&z[ZA(i)] = make_float2(pr * mf, pi * mf);
    }
    // masked slots: i = 4*(s>>1) + 2 + (s&1); p==2 keeps mf=1
#pragma unroll
    for (int k = 0; k < 8; ++k) {
        const int s = tid + (k << 8);
        const int i = ((s >> 1) << 2) | 2 | (s & 1);
        if (i == 2) {   // only tid==0, k==0
            const float2 X = Xrow[2];
            const float2 H = Hrow[2];
            const float2 C = *(const float2*)&z[ZA(2)];
            *(float2*)&z[ZA(2)] = make_float2(X.x * H.x - X.y * H.y + C.x,
                                              X.x * H.y + X.y * H.x + C.y);
        } else {
            *(float2*)&z[ZA(i)] = make_float2(0.0f, 0.0f);
        }
    }
    __syncthreads();

    fft_inv6(z, tw, tid);    // analytic signal (unscaled by 1/N)

    // ---- emit phase (fp32) or amplitude (bf16)
    const float inv_n = 1.0f / 4096.0f;
    if (band < N_PHA) {
        float* dst = pha + (bc * N_PHA + band) * T_LEN;
        for (int i = tid; i < 4096; i += 256) {
            const float2 zz = *(const float2*)&z[ZA(i)];
            dst[i] = fast_atan2f(zz.y, zz.x);    // scale cancels in atan2
        }
    } else {
        unsigned short* dst = amp_bf + (bc * N_AMP + (band - N_PHA)) * T_LEN;
        for (int i = tid; i < 4096; i += 256) {
            const float2 zz = *(const float2*)&z[ZA(i)];
            dst[i] = f2bf(sqrtf(zz.x * zz.x + zz.y * zz.y) * inv_n);
        }
    }
}

// ---------------------------------------------------------------------------
// Fallback main (verbatim R2): inline corr loops. Used only if ws too small.
// ---------------------------------------------------------------------------
__global__ __launch_bounds__(256, 4) void spectral_main_inline(
    const float* __restrict__ x,          // (BC, T)
    const float* __restrict__ filt,       // (20, 513)
    const float2* __restrict__ Xs,        // (BC, 4096)
    const float2* __restrict__ Hs,        // (20, 4096)
    float* __restrict__ pha,              // (BC, 10, T) fp32
    unsigned short* __restrict__ amp_bf)  // (BC, 10, T) bf16 bits
{
    __shared__ float z[8704];
    __shared__ float xe[512];
    __shared__ float fb[FIR_L];

    const int tid  = threadIdx.x;
    const int bc   = blockIdx.x / N_BANDS;
    const int band = blockIdx.x % N_BANDS;
    const float2* tw = twg_dev;

    const float* xrow = x + bc * T_LEN;
    for (int i = tid; i < 512; i += 256)
        xe[i] = (i < 256) ? xrow[i] : xrow[3584 + i];
    for (int i = tid; i < FIR_L; i += 256) fb[i] = filt[band * FIR_L + i];
    __syncthreads();

    float cf = 0.0f, ct = 0.0f;
    for (int l = 0; l <= 255 - tid; ++l)
        cf = fmaf(fb[l], xe[256 + tid + l], cf);
    for (int j = 0; j <= tid; ++j)
        ct = fmaf(fb[512 - tid + j], xe[j], ct);

    fft_fwd_pass1_sparse(z, tw, tid, make_float2(-cf, 0.0f), make_float2(-ct, 0.0f));
    __syncthreads();
    fft_fwd_passes(z, tw, tid, 2);

    const float2* Xrow = Xs + bc * 4096;
    const float2* Hrow = Hs + band * 4096;
    for (int i = tid; i < 4096; i += 256) {
        const float2 X = Xrow[i];
        const float2 H = Hrow[i];
        const float2 C = *(const float2*)&z[ZA(i)];
        float pr = X.x * H.x - X.y * H.y + C.x;
        float pi = X.x * H.y + X.y * H.x + C.y;
        const int m4 = i & 3;
        const float mf = (i == 0 || i == 2) ? 1.0f : (m4 < 2 ? 2.0f : 0.0f);
        *(float2*)&z[ZA(i)] = make_float2(pr * mf, pi * mf);
    }
    __syncthreads();

    fft_inv6(z, tw, tid);

    const float inv_n = 1.0f / 4096.0f;
    if (band < N_PHA) {
        float* dst = pha + (bc * N_PHA + band) * T_LEN;
        for (int i = tid; i < 4096; i += 256) {
            const float2 zz = *(const float2*)&z[ZA(i)];
            dst[i] = fast_atan2f(zz.y, zz.x);
        }
    } else {
        unsigned short* dst = amp_bf + (bc * N_AMP + (band - N_PHA)) * T_LEN;
        for (int i = tid; i < 4096; i += 256) {
            const float2 zz = *(const float2*)&z[ZA(i)];
            dst[i] = f2bf(sqrtf(zz.x * zz.x + zz.y * zz.y) * inv_n);
        }
    }
}

// ---------------------------------------------------------------------------
// Kernel 2: per (bc, pha-band): 3-hot soft phase binning + einsum via MFMA.
// 512 threads / 8 waves per block (verbatim R2).
// ---------------------------------------------------------------------------
__global__ __launch_bounds__(512) void bin_mi_mfma(
    const float* __restrict__ pha,             // (BC, 10, T) fp32
    const unsigned short* __restrict__ amp_bf, // (BC, 10, T) bf16 bits
    float* __restrict__ out)                   // (BC, 10, 10)
{
    const int tid  = threadIdx.x;
    const int lane = tid & 63;
    const int wv   = tid >> 6;        // 0..7
    const int bc   = blockIdx.x / N_PHA;
    const int p    = blockIdx.x % N_PHA;

    __shared__ unsigned int wbufW[8][18 * 68];
    __shared__ float psum[8][11][N_BINS];
    __shared__ float asum[11][N_BINS];

    const float* phrow = pha + (bc * N_PHA + p) * T_LEN;
    const unsigned short* arow = amp_bf + bc * N_AMP * T_LEN;

    const float PI_F  = 3.14159274101257324f;
    const float INVD  = 2.8647889756541160f;   // 9/pi
    const float DELTA = 0.34906585039886590f;  // 2pi/18
    const float C1    = 12.184696791468343f;   // DELTA^2 / 0.01
    const float C2    = 69.813170079773180f;   // 2*DELTA / 0.01

    const int m_ = lane & 15;
    const int q_ = lane >> 4;
    const int n_ = lane & 15;

    short8 zero8;
#pragma unroll
    for (int j = 0; j < 8; ++j) zero8[j] = 0;
    short8 ones8;
#pragma unroll
    for (int j = 0; j < 8; ++j) ones8[j] = (short)0x3F80;   // bf16 1.0

    f32x4 acc0 = {0.f, 0.f, 0.f, 0.f};   // bins 0..15
    f32x4 acc1 = {0.f, 0.f, 0.f, 0.f};   // bins 16..17

    const int base_t = wv * 512;
    unsigned short* wh = (unsigned short*)&wbufW[wv][0];

    float2 pp[4];
#pragma unroll
    for (int c = 0; c < 4; ++c)
        pp[c] = *(const float2*)&phrow[base_t + c * 128 + lane * 2];

    for (int chunk = 0; chunk < 4; ++chunk) {
        const int cb = base_t + chunk * 128;

        short8 af[4];
#pragma unroll
        for (int s = 0; s < 4; ++s) {
            const int tA = cb + s * 32 + q_ * 8;
            if (m_ < N_AMP)       af[s] = *(const short8*)(arow + m_ * T_LEN + tA);
            else if (m_ == N_AMP) af[s] = ones8;
            else                  af[s] = zero8;
        }

#pragma unroll
        for (int k = 0; k < N_BINS; ++k)
            wbufW[wv][k * 68 + lane] = 0u;

#pragma unroll
        for (int h = 0; h < 2; ++h) {
            const float ph = h ? pp[chunk].y : pp[chunk].x;
            float u  = (ph + PI_F) * INVD;       // in [0, 18]
            float jf = floorf(u);
            float d  = (u - jf - 0.5f) * DELTA;
            int j0 = (int)jf;
            if (j0 >= N_BINS) j0 -= N_BINS;      // ph == +pi wraps
            const int jm = (j0 == 0) ? N_BINS - 1 : j0 - 1;
            const int jp = (j0 == N_BINS - 1) ? 0 : j0 + 1;
            const float em = expf(-C1 - C2 * d);
            const float ep = expf(-C1 + C2 * d);
            const float inv = 1.0f / (1.0f + em + ep);
            wh[(j0 * 68 + lane) * 2 + h] = f2bf(inv);
            wh[(jm * 68 + lane) * 2 + h] = f2bf(em * inv);
            wh[(jp * 68 + lane) * 2 + h] = f2bf(ep * inv);
        }
        __builtin_amdgcn_wave_barrier();

#pragma unroll
        for (int s = 0; s < 4; ++s) {
            const int woff = s * 16 + q_ * 4;
            short8 bfrag0 = *(const short8*)&wbufW[wv][n_ * 68 + woff];
            short8 bfrag1 = (n_ < 2)
                ? *(const short8*)&wbufW[wv][(16 + n_) * 68 + woff]
                : zero8;
            acc0 = __builtin_amdgcn_mfma_f32_16x16x32_bf16(af[s], bfrag0, acc0, 0, 0, 0);
            acc1 = __builtin_amdgcn_mfma_f32_16x16x32_bf16(af[s], bfrag1, acc1, 0, 0, 0);
        }
        __builtin_amdgcn_wave_barrier();
    }

#pragma unroll
    for (int r = 0; r < 4; ++r) {
        const int m = q_ * 4 + r;
        if (m < 11) {
            psum[wv][m][n_] = acc0[r];
            if (n_ < 2) psum[wv][m][16 + n_] = acc1[r];
        }
    }
    __syncthreads();

    if (tid < 11 * N_BINS) {
        const int m = tid / N_BINS;
        const int k = tid % N_BINS;
        float s = 0.0f;
#pragma unroll
        for (int w = 0; w < 8; ++w) s += psum[w][m][k];
        asum[m][k] = s;
    }
    __syncthreads();

    if (tid < N_AMP) {
        float ma[N_BINS];
        float msum = 0.0f;
#pragma unroll
        for (int k = 0; k < N_BINS; ++k) {
            float m = asum[tid][k] / (asum[10][k] + 1e-8f);
            ma[k] = m;
            msum += m;
        }
        const float inv = 1.0f / (msum + 1e-8f);
        float acc = 0.0f;
#pragma unroll
        for (int k = 0; k < N_BINS; ++k) {
            float pk = ma[k] * inv;
            acc = fmaf(pk, logf(pk + 1e-8f), acc);
        }
        const float logk = 2.89037175789124f;    // log(18)
        out[(bc * N_PHA + p) * N_AMP + tid] = (logk + acc) / logk;
    }
}

extern "C" void kernel_launch(void* const* d_in, const int* in_sizes, int n_in,
                              void* d_out, int out_size, void* d_ws, size_t ws_size,
                              hipStream_t stream) {
    const float* x    = (const float*)d_in[0];   // (4,16,4096) f32
    const float* filt = (const float*)d_in[1];   // (20,513) f32
    float* out = (float*)d_out;                  // (4,16,10,10) f32

    // ws layout: pha fp32 | amp bf16 | Xspec | Hspec | corr  (~21.1 MB)
    float* pha = (float*)d_ws;                               // BC*10*T fp32
    unsigned short* amp_bf = (unsigned short*)(pha + BC * N_PHA * T_LEN);
    float2* Xs = (float2*)(amp_bf + BC * N_AMP * T_LEN);     // BC*4096 cplx
    float2* Hs = Xs + BC * 4096;                             // 20*4096 cplx
    float* corr = (float*)(Hs + N_BANDS * 4096);             // BC*20*2*256 f32

    const size_t need = (size_t)BC * N_PHA * T_LEN * 4
                      + (size_t)BC * N_AMP * T_LEN * 2
                      + (size_t)BC * 4096 * 8
                      + (size_t)N_BANDS * 4096 * 8
                      + (size_t)BC * N_BANDS * 2 * 256 * 4;   // 21,102,592
    const bool fits = (ws_size >= need);

    if (fits) {
        spectral_pre<<<BC + N_BANDS + 1 + BC * N_BANDS, 256, 0, stream>>>(x, filt, Xs, Hs, corr);
        spectral_main_pre<<<BC * N_BANDS, 256, 0, stream>>>(corr, Xs, Hs, pha, amp_bf);
    } else {
        spectral_pre<<<BC + N_BANDS + 1, 256, 0, stream>>>(x, filt, Xs, Hs, corr);
        spectral_main_inline<<<BC * N_BANDS, 256, 0, stream>>>(x, filt, Xs, Hs, pha, amp_bf);
    }
    bin_mi_mfma<<<BC * N_PHA, 512, 0, stream>>>(pha, amp_bf, out);
}